// Round 13
// baseline (1324.898 us; speedup 1.0000x reference)
//
#include <hip/hip_runtime.h>
#include <hip/hip_bf16.h>
#include <float.h>

#define NPTS 4096
#define NB 4
#define KNN 20

typedef __attribute__((ext_vector_type(8))) short short8v;   // 8 bf16 in 4 VGPRs
typedef __attribute__((ext_vector_type(4))) float f32x4;
typedef unsigned long long u64;

#define MFMA_B16(acc, a, b) acc = __builtin_amdgcn_mfma_f32_16x16x32_bf16((a), (b), (acc), 0, 0, 0)

// 6-product 3-plane bf16 sim: h·h' + h·m' + m·h' + h·l' + l·h' + m·m'
// A/B arrays: [0]=h0 [1]=h1 [2]=m0 [3]=m1 [4]=l0 [5]=l1 (halves of K=64)
#define SIM6(P, R, A, B) \
    MFMA_B16(P, A[0], B[0]); MFMA_B16(R, A[1], B[1]); \
    MFMA_B16(P, A[0], B[2]); MFMA_B16(R, A[1], B[3]); \
    MFMA_B16(P, A[2], B[0]); MFMA_B16(R, A[3], B[1]); \
    MFMA_B16(P, A[0], B[4]); MFMA_B16(R, A[1], B[5]); \
    MFMA_B16(P, A[4], B[0]); MFMA_B16(R, A[5], B[1]); \
    MFMA_B16(P, A[2], B[2]); MFMA_B16(R, A[3], B[3]);

__device__ __forceinline__ float lrelu(float x) { return x > 0.f ? x : 0.2f * x; }

__device__ __forceinline__ void atomicMaxF(float* addr, float val) {
    int* ia = (int*)addr;
    int old = *ia;
    while (__int_as_float(old) < val) {
        int assumed = old;
        old = atomicCAS(ia, assumed, __float_as_int(val));
        if (old == assumed) break;
    }
}

// round-to-nearest-even fp32 -> bf16 bits
__device__ __forceinline__ unsigned bf16rne(float x) {
    unsigned u = __float_as_uint(x);
    return (u + 0x7fffu + ((u >> 16) & 1u)) >> 16;
}

// fp32 -> uint key where SMALLER key = LARGER float (total order, no NaN inputs).
// key64 = (key32<<32)|idx : ascending sort = (value desc, idx asc) == top_k tie order.
__device__ __forceinline__ unsigned sortkey_desc(float v) {
    unsigned u = __float_as_uint(v);
    unsigned s = (u & 0x80000000u) ? ~u : (u | 0x80000000u);  // ascending int == ascending float
    return ~s;                                                 // invert: ascending key == descending float
}

// 64-lane bitonic sort, ascending by u64 key. Each lane holds one element.
__device__ __forceinline__ u64 bitonic64(u64 e, int ln) {
#pragma unroll
    for (int k = 2; k <= 64; k <<= 1) {
#pragma unroll
        for (int j = k >> 1; j > 0; j >>= 1) {
            u64 o = __shfl_xor(e, j);
            bool keepMin = (((ln & k) == 0) == ((ln & j) == 0));
            u64 mn = e < o ? e : o;
            u64 mx = e < o ? o : e;
            e = keepMin ? mn : mx;
        }
    }
    return e;
}

// Merge current top-20 (lanes 0..19 of 'topk', sorted asc by key) with 'cnt' buffered
// candidates in LDS 'buf'. Updates topk (lanes 0..19), threshold key, resets cnt.
__device__ __forceinline__ void topk_merge(u64& topk, unsigned& thk, int& cnt,
                                           const u64* __restrict__ buf, int ln) {
    u64 e = (ln < 20) ? topk : ((ln - 20) < cnt ? buf[ln - 20] : ~0ull);
    e = bitonic64(e, ln);
    topk = e;
    u64 e19 = __shfl(e, 19);
    thk = (unsigned)(e19 >> 32);
    cnt = 0;
}

// ---------------- generic transpose: dst[c][r] = src[r][c0..] ----------------
__global__ void k_transp(const float* __restrict__ src, float* __restrict__ dst,
                         int rows, int srcld, int cols) {
    int i = blockIdx.x * 256 + threadIdx.x;
    if (i >= rows * cols) return;
    int r = i % rows, c = i / rows;              // writes coalesced
    dst[c * rows + r] = src[(size_t)r * srcld + c];
}

// ---------------- prep for euclid knn: point-major pack {x0..x5, sq, 0} ----------------
__global__ void k_prep(const float* __restrict__ x, float* __restrict__ xpm8) {
    int i = blockIdx.x * 256 + threadIdx.x;   // b*N + n
    int b = i >> 12, n = i & 4095;
    const float* xb = x + b * 6 * NPTS;
    float v[6]; float s = 0.f;
#pragma unroll
    for (int c = 0; c < 6; c++) { v[c] = xb[c * NPTS + n]; s += v[c] * v[c]; }
    float* o = xpm8 + (size_t)i * 8;
    *(float4*)(o)     = make_float4(v[0], v[1], v[2], v[3]);
    *(float4*)(o + 4) = make_float4(v[4], v[5], s, 0.f);
}

// ---------------- euclid knn v6: point-major b128 loads + bootstrap + batched bitonic ----------------
__global__ __launch_bounds__(256) void k_knn_euclid(const float* __restrict__ xpm8,
                                                    int* __restrict__ idx) {
    __shared__ u64 ebuf[4][44];
    int t = threadIdx.x;
    int w = t >> 6, ln = t & 63;
    int qid = blockIdx.x * 4 + w;
    int b = qid >> 12;
    const float* pb = xpm8 + (((size_t)b) << 12) * 8;
    const float* qp = xpm8 + (size_t)qid * 8;
    float4 qlo = *(const float4*)qp;
    float4 qhi = *(const float4*)(qp + 4);
    float sqn = qhi.z;
    u64 topk;
    unsigned thk;
    int cnt = 0;
    u64* bq = ebuf[w];
    // bootstrap: exact top-20 of candidates 0..63 via one full sort
    {
        const float* cp = pb + ln * 8;
        float4 lo = *(const float4*)cp, hi = *(const float4*)(cp + 4);
        float dot = qlo.x * lo.x + qlo.y * lo.y + qlo.z * lo.z + qlo.w * lo.w
                  + qhi.x * hi.x + qhi.y * hi.y;
        float sv = -(sqn - 2.f * dot + hi.z);
        u64 e = ((u64)sortkey_desc(sv) << 32) | (unsigned)ln;
        e = bitonic64(e, ln);
        topk = e;
        thk = (unsigned)(__shfl(e, 19) >> 32);
    }
    for (int t0 = 64; t0 < NPTS; t0 += 64) {
        int m = t0 + ln;
        const float* cp = pb + (size_t)m * 8;
        float4 lo = *(const float4*)cp, hi = *(const float4*)(cp + 4);
        float dot = qlo.x * lo.x + qlo.y * lo.y + qlo.z * lo.z + qlo.w * lo.w
                  + qhi.x * hi.x + qhi.y * hi.y;
        float sv = -(sqn - 2.f * dot + hi.z);        // top-k of -d, exactly as reference
        unsigned key = sortkey_desc(sv);
        bool pass = key < thk;                        // strictly better than current 20th
        u64 mask = __ballot(pass);
        if (!mask) continue;
        u64 key64 = ((u64)key << 32) | (unsigned)m;
        int cA = __popcll(mask & 0xFFFFFFFFull);
        int cB = __popcll(mask >> 32);
        if (cA) {
            if (cnt + cA > 44) topk_merge(topk, thk, cnt, bq, ln);
            if (pass && ln < 32) bq[cnt + __popcll(mask & ((1ull << ln) - 1))] = key64;
            cnt += cA;
        }
        if (cB) {
            if (cnt + cB > 44) topk_merge(topk, thk, cnt, bq, ln);
            if (pass && ln >= 32) bq[cnt + __popcll((mask >> 32) & ((1ull << (ln - 32)) - 1))] = key64;
            cnt += cB;
        }
    }
    if (cnt) topk_merge(topk, thk, cnt, bq, ln);
    if (ln < KNN) idx[qid * KNN + ln] = (int)(topk & 0xFFFFFFFFull);
}

// ---------------- cosine knn v21: 32 queries/block, 8 waves (grid-occupancy fix) ----------------
// xsT: [b][tile16][plane(3)][half(2)][kg(4)][lp(16)][8ch] bf16. Fragment load = base + ln*8.
// Block: 32 queries, 8 waves (512 thr). 16 strips x 256 cands; wave w computes cand-tiles
// {2w, 2w+1} of each strip for all 32 queries (48 MFMA / 12 B-loads), then scans queries
// w*4..w*4+3. vs v20: same work, 2x the waves -> latency chains (merges/ballots) hidden.
__global__ __launch_bounds__(512) void k_knn_cos(const unsigned short* __restrict__ xsT,
                                                 int* __restrict__ idx) {
    __shared__ float simb[32][260];      // 33.3 KB; rows 0-15 = set0, 16-31 = set1
    __shared__ u64 bufp[32][44];         // 11.3 KB per-query candidate buffers
    int t = threadIdx.x;
    int w = t >> 6, ln = t & 63;         // w in [0,8)
    int b = blockIdx.x >> 7;             // 128 blocks per batch
    int q0blk = (blockIdx.x & 127) * 32;
    int lp = ln & 15;                    // point-in-tile (A row / B col)
    const unsigned short* xsb = xsT + (size_t)b * 256 * 3072;
    // A fragments: two query tiles x 6 coalesced 1KB loads
    const unsigned short* qt0 = xsb + (size_t)(q0blk >> 4) * 3072 + ln * 8;
    const unsigned short* qt1 = qt0 + 3072;
    short8v A0[6], A1[6];
#pragma unroll
    for (int p = 0; p < 6; p++) {
        A0[p] = *(const short8v*)(qt0 + p * 512);
        A1[p] = *(const short8v*)(qt1 + p * 512);
    }
    u64 topk[4];
    unsigned thk[4];
    int cnt[4] = {0, 0, 0, 0};
    for (int strip = 0; strip < 16; strip++) {
        // ---- compute: wave w owns cand-tiles {2w, 2w+1} of this strip ----
        {
            int tt0 = w * 2;                     // strip-local tile index (pair base)
            const unsigned short* tb0 = xsb + (size_t)(strip * 16 + tt0) * 3072 + ln * 8;
            const unsigned short* tb1 = tb0 + 3072;
            short8v Ba[6], Bb[6];
#pragma unroll
            for (int p = 0; p < 6; p++) {
                Ba[p] = *(const short8v*)(tb0 + p * 512);
                Bb[p] = *(const short8v*)(tb1 + p * 512);
            }
            f32x4 p00 = {0.f,0.f,0.f,0.f}, r00 = {0.f,0.f,0.f,0.f};
            f32x4 p01 = {0.f,0.f,0.f,0.f}, r01 = {0.f,0.f,0.f,0.f};
            f32x4 p10 = {0.f,0.f,0.f,0.f}, r10 = {0.f,0.f,0.f,0.f};
            f32x4 p11 = {0.f,0.f,0.f,0.f}, r11 = {0.f,0.f,0.f,0.f};
            SIM6(p00, r00, A0, Ba); SIM6(p01, r01, A0, Bb);
            SIM6(p10, r10, A1, Ba); SIM6(p11, r11, A1, Bb);
            f32x4 s00 = p00 + r00, s01 = p01 + r01;
            f32x4 s10 = p10 + r10, s11 = p11 + r11;
            // D layout: col = lane&15 (candidate), row = (lane>>4)*4 + reg (query)
            int row = (ln >> 4) * 4;
            int colL = tt0 * 16 + lp;            // strip-local column
#pragma unroll
            for (int r = 0; r < 4; r++) {
                simb[row + r][colL]           = s00[r];
                simb[row + r][colL + 16]      = s01[r];
                simb[16 + row + r][colL]      = s10[r];
                simb[16 + row + r][colL + 16] = s11[r];
            }
        }
        __syncthreads();
        // ---- select: wave w scans queries w*4..w*4+3 over the 256-cand strip ----
#pragma unroll
        for (int q = 0; q < 4; q++) {
            int lq = w * 4 + q;
            u64* bq = bufp[lq];
            int j0 = 0;
            if (strip == 0) {
                // exact top-20 of candidates 0..63 via one full sort
                float sv = simb[lq][ln];
                u64 e = ((u64)sortkey_desc(sv) << 32) | (unsigned)ln;
                e = bitonic64(e, ln);
                topk[q] = e;
                thk[q] = (unsigned)(__shfl(e, 19) >> 32);
                j0 = 1;
            }
            for (int j = j0; j < 4; j++) {
                float sv = simb[lq][j * 64 + ln];
                unsigned key = sortkey_desc(sv);
                bool pass = key < thk[q];              // strictly better than 20th
                u64 mask = __ballot(pass);
                if (!mask) continue;
                u64 key64 = ((u64)key << 32) | (unsigned)(strip * 256 + j * 64 + ln);
                int cA = __popcll(mask & 0xFFFFFFFFull);
                int cB = __popcll(mask >> 32);
                if (cA) {
                    if (cnt[q] + cA > 44) topk_merge(topk[q], thk[q], cnt[q], bq, ln);
                    if (pass && ln < 32) bq[cnt[q] + __popcll(mask & ((1ull << ln) - 1))] = key64;
                    cnt[q] += cA;
                }
                if (cB) {
                    if (cnt[q] + cB > 44) topk_merge(topk[q], thk[q], cnt[q], bq, ln);
                    if (pass && ln >= 32) bq[cnt[q] + __popcll((mask >> 32) & ((1ull << (ln - 32)) - 1))] = key64;
                    cnt[q] += cB;
                }
            }
        }
        __syncthreads();
    }
#pragma unroll
    for (int q = 0; q < 4; q++) {
        int lq = w * 4 + q;
        if (cnt[q]) topk_merge(topk[q], thk[q], cnt[q], bufp[lq], ln);
        if (ln < KNN) {
            int qid = (b << 12) + q0blk + lq;
            idx[(size_t)qid * KNN + ln] = (int)(topk[q] & 0xFFFFFFFFull);
        }
    }
}

// ---------------- normalize 64 cols of point-major xcpm -> tile-packed 3-plane bf16 xsT ----------------
// xsT[b][tile16][plane][half][kg][lp][8ch]: x_norm = h+m+l (RNE at each stage)
__global__ void k_normalize(const float* __restrict__ xcpm, int coff,
                            unsigned short* __restrict__ xsT) {
    int pid = blockIdx.x * 256 + threadIdx.x;
    int b = pid >> 12, n = pid & 4095;
    const float* p = xcpm + (size_t)pid * 192 + coff;
    float s = 0.f;
#pragma unroll
    for (int c4 = 0; c4 < 16; c4++) {
        float4 v = *(const float4*)(p + c4 * 4);
        s += v.x * v.x + v.y * v.y + v.z * v.z + v.w * v.w;
    }
    float inv = 1.f / (sqrtf(s) + 1e-8f);
    unsigned short* q = xsT + (size_t)(b * 256 + (n >> 4)) * 3072 + (n & 15) * 8;
#pragma unroll
    for (int c4 = 0; c4 < 16; c4++) {
        float4 v = *(const float4*)(p + c4 * 4);
        float f[4] = {v.x * inv, v.y * inv, v.z * inv, v.w * inv};
        unsigned short hh[4], mm[4], ll[4];
#pragma unroll
        for (int j = 0; j < 4; j++) {
            float x = f[j];
            unsigned hb = bf16rne(x);
            float hf = __uint_as_float(hb << 16);
            float r1 = x - hf;                       // exact
            unsigned mb = bf16rne(r1);
            float mf = __uint_as_float(mb << 16);
            float r2 = r1 - mf;                      // exact
            unsigned lb = bf16rne(r2);
            hh[j] = (unsigned short)hb; mm[j] = (unsigned short)mb; ll[j] = (unsigned short)lb;
        }
        int h = c4 >> 3, kg = (c4 >> 1) & 3, off4 = (c4 & 1) * 4;
        int base = h * 512 + kg * 128 + off4;        // plane 0; +1024/short-plane stride
        *(ushort4*)(q + base)        = make_ushort4(hh[0], hh[1], hh[2], hh[3]);
        *(ushort4*)(q + base + 1024) = make_ushort4(mm[0], mm[1], mm[2], mm[3]);
        *(ushort4*)(q + base + 2048) = make_ushort4(ll[0], ll[1], ll[2], ll[3]);
    }
}

// ---------------- EdgeConv 1: 6ch (channel-major x), 12->64->64, wave-per-point ----------------
__global__ __launch_bounds__(256) void k_edge1(const float* __restrict__ x,
    const float* __restrict__ w0, const float* __restrict__ s0, const float* __restrict__ o0,
    const float* __restrict__ w1, const float* __restrict__ s1, const float* __restrict__ o1,
    const int* __restrict__ idx, float* __restrict__ xcpm) {
    __shared__ float es[4][16];
    __shared__ float h0s[4][64];
    int t = threadIdx.x;
    int w = t >> 6, o = t & 63;
    int pid = blockIdx.x * 4 + w;
    int b = pid >> 12, n = pid & 4095;
    const float* xb = x + b * 6 * NPTS;
    float w0r[12];
    const float* w0p = w0 + o * 12;
#pragma unroll
    for (int c4 = 0; c4 < 3; c4++) {
        float4 v = *(const float4*)(w0p + c4 * 4);
        w0r[c4 * 4] = v.x; w0r[c4 * 4 + 1] = v.y; w0r[c4 * 4 + 2] = v.z; w0r[c4 * 4 + 3] = v.w;
    }
    float w1r[64];
    const float* w1p = w1 + o * 64;
#pragma unroll
    for (int c4 = 0; c4 < 16; c4++) {
        float4 v = *(const float4*)(w1p + c4 * 4);
        w1r[c4 * 4] = v.x; w1r[c4 * 4 + 1] = v.y; w1r[c4 * 4 + 2] = v.z; w1r[c4 * 4 + 3] = v.w;
    }
    float sv0 = s0[o], ov0 = o0[o], sv1 = s1[o], ov1 = o1[o];
    float cv = 0.f;
    if (o < 6) { cv = xb[o * NPTS + n]; es[w][6 + o] = cv; }
    if (o >= 12 && o < 16) es[w][o] = 0.f;
    float acc = -FLT_MAX;
    const int* ib = idx + pid * KNN;
    for (int kk = 0; kk < KNN; kk++) {
        int j = ib[kk] & 4095;
        if (o < 6) es[w][o] = xb[o * NPTS + j] - cv;
        float h = 0.f;
#pragma unroll
        for (int c4 = 0; c4 < 3; c4++) {
            float4 e4 = *(const float4*)&es[w][c4 * 4];
            h += w0r[c4 * 4] * e4.x + w0r[c4 * 4 + 1] * e4.y + w0r[c4 * 4 + 2] * e4.z + w0r[c4 * 4 + 3] * e4.w;
        }
        h = lrelu(h * sv0 + ov0);
        h0s[w][o] = h;
        float h2 = 0.f;
#pragma unroll
        for (int c4 = 0; c4 < 16; c4++) {
            float4 h4 = *(const float4*)&h0s[w][c4 * 4];
            h2 += w1r[c4 * 4] * h4.x + w1r[c4 * 4 + 1] * h4.y + w1r[c4 * 4 + 2] * h4.z + w1r[c4 * 4 + 3] * h4.w;
        }
        h2 = lrelu(h2 * sv1 + ov1);
        acc = fmaxf(acc, h2);
    }
    xcpm[(size_t)pid * 192 + o] = acc;
}

// ---------------- EdgeConv 2/3 v3: channel-outer / neighbor-inner, no weight spills ----------------
// Stage 20 neighbor diffs in LDS once; 20 per-neighbor accumulators in VGPRs; the thread's
// weight float4 is re-loaded per channel-tile per point (L1-hot) instead of spilling 128 regs.
__global__ __launch_bounds__(256) void k_edge23(const float* __restrict__ xcpm,
    const float* __restrict__ w0, const float* __restrict__ s0, const float* __restrict__ o0,
    const float* __restrict__ w1, const float* __restrict__ s1, const float* __restrict__ o1,
    const int* __restrict__ idx, int ci, int co) {
    __shared__ float cs[4][64];          // 1 KB
    __shared__ float es[4][KNN][64];     // 20 KB neighbor diffs
    __shared__ float h0s[4][KNN][64];    // 20 KB layer-0 activations
    int t = threadIdx.x;
    int w = t >> 6, o = t & 63;
    int pid = blockIdx.x * 4 + w;
    int b = pid >> 12;
    float sv0 = s0[o], ov0 = o0[o], sv1 = s1[o], ov1 = o1[o];
    float cv = xcpm[(size_t)pid * 192 + ci + o];
    cs[w][o] = cv;
    // stage neighbor diffs: 20 independent coalesced 256B gathers
    const int* ib = idx + pid * KNN;
    const float* xb = xcpm + ((size_t)(b * 4096)) * 192 + ci;
#pragma unroll
    for (int j = 0; j < KNN; j++) {
        int jn = ib[j] & 4095;
        es[w][j][o] = xb[(size_t)jn * 192 + o] - cv;
    }
    // center contribution (second half of w0 row)
    const float* w0p = w0 + o * 128;
    float h0b;
    {
        float hb[4] = {0.f, 0.f, 0.f, 0.f};
#pragma unroll
        for (int c4 = 0; c4 < 16; c4++) {
            float4 wv = *(const float4*)(w0p + 64 + c4 * 4);
            float4 c4v = *(const float4*)&cs[w][c4 * 4];
            hb[c4 & 3] += wv.x * c4v.x + wv.y * c4v.y + wv.z * c4v.z + wv.w * c4v.w;
        }
        h0b = (hb[0] + hb[1]) + (hb[2] + hb[3]);
    }
    // layer 0: 20 parallel accumulator chains, weight float4 reloaded per channel tile
    float h0a[KNN];
#pragma unroll
    for (int j = 0; j < KNN; j++) h0a[j] = h0b;
    for (int c4 = 0; c4 < 16; c4++) {
        float4 wv = *(const float4*)(w0p + c4 * 4);
#pragma unroll
        for (int j = 0; j < KNN; j++) {
            float4 e = *(const float4*)&es[w][j][c4 * 4];
            h0a[j] += wv.x * e.x + wv.y * e.y + wv.z * e.z + wv.w * e.w;
        }
    }
#pragma unroll
    for (int j = 0; j < KNN; j++) h0s[w][j][o] = lrelu(h0a[j] * sv0 + ov0);
    // layer 1 (wave-synchronous LDS reuse)
    const float* w1p = w1 + o * 64;
    float h1a[KNN];
#pragma unroll
    for (int j = 0; j < KNN; j++) h1a[j] = 0.f;
    for (int c4 = 0; c4 < 16; c4++) {
        float4 wv = *(const float4*)(w1p + c4 * 4);
#pragma unroll
        for (int j = 0; j < KNN; j++) {
            float4 e = *(const float4*)&h0s[w][j][c4 * 4];
            h1a[j] += wv.x * e.x + wv.y * e.y + wv.z * e.z + wv.w * e.w;
        }
    }
    float acc = -FLT_MAX;
#pragma unroll
    for (int j = 0; j < KNN; j++) acc = fmaxf(acc, lrelu(h1a[j] * sv1 + ov1));
    float* outp = (float*)xcpm;
    outp[(size_t)pid * 192 + co + o] = acc;
}

// ---------------- init g to -inf ----------------
__global__ void k_init_g(float* __restrict__ g) {
    g[blockIdx.x * 256 + threadIdx.x] = -FLT_MAX;
}

// ---------------- w4+pool v2: outer-product 16o x 4tn, 64-pt staged tile, wT4 ----------------
__global__ __launch_bounds__(256) void k_w4pool(const float* __restrict__ xc,
                                                const float* __restrict__ wT4,
                                                const float* __restrict__ b4,
                                                float* __restrict__ g) {
    __shared__ float xcs[192 * 68];   // 64 points, stride 68 (52.2 KB)
    int t = threadIdx.x;
    int b = blockIdx.y;
    int n0 = blockIdx.x * 64;
    const float* xb = xc + (size_t)(b * 4096 + n0) * 192;
    for (int i = t; i < 3072; i += 256) {
        int pt = i / 48, c4 = i - pt * 48;
        float4 v = *(const float4*)(xb + pt * 192 + c4 * 4);
        xcs[(c4 * 4 + 0) * 68 + pt] = v.x; xcs[(c4 * 4 + 1) * 68 + pt] = v.y;
        xcs[(c4 * 4 + 2) * 68 + pt] = v.z; xcs[(c4 * 4 + 3) * 68 + pt] = v.w;
    }
    __syncthreads();
    int o0 = (t >> 2) * 16, qd = t & 3;
    float4 bb[4];
#pragma unroll
    for (int k = 0; k < 4; k++) bb[k] = *(const float4*)(b4 + o0 + k * 4);
    float mx[16];
#pragma unroll
    for (int oo = 0; oo < 16; oo++) mx[oo] = -FLT_MAX;
    for (int sub = 0; sub < 4; sub++) {
        int tn0 = sub * 16 + qd * 4;
        float4 acc[16];
#pragma unroll
        for (int oo = 0; oo < 16; oo++) acc[oo] = (float4){0, 0, 0, 0};
        for (int c = 0; c < 192; c++) {
            float4 x4 = *(const float4*)&xcs[c * 68 + tn0];
            const float* wr = wT4 + c * 1024 + o0;
            float4 wq[4];
#pragma unroll
            for (int k = 0; k < 4; k++) wq[k] = *(const float4*)(wr + k * 4);
#pragma unroll
            for (int oo = 0; oo < 16; oo++) {
                float wv = ((const float*)wq)[oo];
                acc[oo].x += wv * x4.x; acc[oo].y += wv * x4.y;
                acc[oo].z += wv * x4.z; acc[oo].w += wv * x4.w;
            }
        }
#pragma unroll
        for (int oo = 0; oo < 16; oo++) {
            float bias = ((const float*)bb)[oo];
            float4 a = acc[oo];
            float h = fmaxf(fmaxf(lrelu(a.x + bias), lrelu(a.y + bias)),
                            fmaxf(lrelu(a.z + bias), lrelu(a.w + bias)));
            mx[oo] = fmaxf(mx[oo], h);
        }
    }
#pragma unroll
    for (int oo = 0; oo < 16; oo++) {
        float v = mx[oo];
        v = fmaxf(v, __shfl_xor(v, 1));
        v = fmaxf(v, __shfl_xor(v, 2));
        if (qd == 0) atomicMaxF(&g[b * 1024 + o0 + oo], v);
    }
}

// ---------------- goff[b][o] = (wf1[o,192:1216] . g[b]) * sf1[o] + of1[o] ----------------
__global__ __launch_bounds__(256) void k_goff(const float* __restrict__ g,
                                              const float* __restrict__ wf1,
                                              const float* __restrict__ sf1,
                                              const float* __restrict__ of1,
                                              float* __restrict__ goff) {
    int bo = blockIdx.x;
    int b = bo >> 9, o = bo & 511;
    int t = threadIdx.x;
    const float* wr = wf1 + (size_t)o * 1216 + 192;
    const float* gb = g + b * 1024;
    float s = 0.f;
    for (int c = t; c < 1024; c += 256) s += wr[c] * gb[c];
    __shared__ float red[4];
    for (int off = 32; off > 0; off >>= 1) s += __shfl_down(s, off);
    if ((t & 63) == 0) red[t >> 6] = s;
    __syncthreads();
    if (t == 0) {
        float tot = red[0] + red[1] + red[2] + red[3];
        goff[bo] = tot * sf1[o] + of1[o];
    }
}

// ---------------- fused tail v2: outer-product register blocking, transposed weights ----------------
#define TP 20
__global__ __launch_bounds__(256) void k_tail(const float* __restrict__ xc,
                                              const float* __restrict__ wf1T,
                                              const float* __restrict__ sf1,
                                              const float* __restrict__ goff,
                                              const float* __restrict__ wf2T,
                                              const float* __restrict__ sf2,
                                              const float* __restrict__ of2,
                                              const float* __restrict__ wf3,
                                              float* __restrict__ out) {
    __shared__ float xcs[192 * TP];      // 15.4 KB
    __shared__ float h1s[512 * TP];      // 40 KB
    __shared__ float h2s[256 * TP];      // 20 KB
    int t = threadIdx.x;
    int b = blockIdx.y;
    int n0 = blockIdx.x * 16;
    const float* xb = xc + (size_t)(b * 4096 + n0) * 192;
    for (int i = t; i < 768; i += 256) {
        int pt = i / 48, c4 = i - pt * 48;
        float4 v = *(const float4*)(xb + pt * 192 + c4 * 4);
        xcs[(c4 * 4 + 0) * TP + pt] = v.x; xcs[(c4 * 4 + 1) * TP + pt] = v.y;
        xcs[(c4 * 4 + 2) * TP + pt] = v.z; xcs[(c4 * 4 + 3) * TP + pt] = v.w;
    }
    __syncthreads();
    // h1: thread = 8 outputs x 4 points
    {
        int o8 = (t >> 2) * 8, tn0 = (t & 3) * 4;
        float4 acc[8];
#pragma unroll
        for (int oo = 0; oo < 8; oo++) acc[oo] = (float4){0, 0, 0, 0};
        for (int c = 0; c < 192; c++) {
            float4 x4 = *(const float4*)&xcs[c * TP + tn0];
            const float* wr = wf1T + c * 512 + o8;
            float4 w0 = *(const float4*)(wr);
            float4 w1 = *(const float4*)(wr + 4);
            float wq[8] = {w0.x, w0.y, w0.z, w0.w, w1.x, w1.y, w1.z, w1.w};
#pragma unroll
            for (int oo = 0; oo < 8; oo++) {
                acc[oo].x += wq[oo] * x4.x; acc[oo].y += wq[oo] * x4.y;
                acc[oo].z += wq[oo] * x4.z; acc[oo].w += wq[oo] * x4.w;
            }
        }
#pragma unroll
        for (int oo = 0; oo < 8; oo++) {
            int o = o8 + oo;
            float s = sf1[o];
            float gv = goff[b * 512 + o];
            float4 r;
            r.x = lrelu(acc[oo].x * s + gv); r.y = lrelu(acc[oo].y * s + gv);
            r.z = lrelu(acc[oo].z * s + gv); r.w = lrelu(acc[oo].w * s + gv);
            *(float4*)&h1s[o * TP + tn0] = r;
        }
    }
    __syncthreads();
    // h2: thread = 4 outputs x 4 points
    {
        int o4 = (t >> 2) * 4, tn0 = (t & 3) * 4;
        float4 acc[4];
#pragma unroll
        for (int oo = 0; oo < 4; oo++) acc[oo] = (float4){0, 0, 0, 0};
        for (int c = 0; c < 512; c++) {
            float4 x4 = *(const float4*)&h1s[c * TP + tn0];
            float4 w = *(const float4*)(wf2T + c * 256 + o4);
            float wq[4] = {w.x, w.y, w.z, w.w};
#pragma unroll
            for (int oo = 0; oo < 4; oo++) {
                acc[oo].x += wq[oo] * x4.x; acc[oo].y += wq[oo] * x4.y;
                acc[oo].z += wq[oo] * x4.z; acc[oo].w += wq[oo] * x4.w;
            }
        }
#pragma unroll
        for (int oo = 0; oo < 4; oo++) {
            int o = o4 + oo;
            float s = sf2[o], of = of2[o];
            float4 r;
            r.x = lrelu(acc[oo].x * s + of); r.y = lrelu(acc[oo].y * s + of);
            r.z = lrelu(acc[oo].z * s + of); r.w = lrelu(acc[oo].w * s + of);
            *(float4*)&h2s[o * TP + tn0] = r;
        }
    }
    __syncthreads();
    // out: 13 x 16
    if (t < 13 * 16) {
        int o = t >> 4, tn = t & 15;
        const float* wr = wf3 + o * 256;
        float acc = 0.f;
        for (int c4 = 0; c4 < 64; c4++) {
            float4 wv = *(const float4*)(wr + c4 * 4);
            acc += wv.x * h2s[(c4 * 4 + 0) * TP + tn] + wv.y * h2s[(c4 * 4 + 1) * TP + tn]
                 + wv.z * h2s[(c4 * 4 + 2) * TP + tn] + wv.w * h2s[(c4 * 4 + 3) * TP + tn];
        }
        out[((size_t)b * 13 + o) * NPTS + n0 + tn] = acc;
    }
}

extern "C" void kernel_launch(void* const* d_in, const int* in_sizes, int n_in,
                              void* d_out, int out_size, void* d_ws, size_t ws_size,
                              hipStream_t stream) {
    const float* x    = (const float*)d_in[0];
    const float* w1_0 = (const float*)d_in[1];
    const float* s1_0 = (const float*)d_in[2];
    const float* o1_0 = (const float*)d_in[3];
    const float* w1_1 = (const float*)d_in[4];
    const float* s1_1 = (const float*)d_in[5];
    const float* o1_1 = (const float*)d_in[6];
    const float* w2_0 = (const float*)d_in[7];
    const float* s2_0 = (const float*)d_in[8];
    const float* o2_0 = (const float*)d_in[9];
    const float* w2_1 = (const float*)d_in[10];
    const float* s2_1 = (const float*)d_in[11];
    const float* o2_1 = (const float*)d_in[12];
    const float* w3_0 = (const float*)d_in[13];
    const float* s3_0 = (const float*)d_in[14];
    const float* o3_0 = (const float*)d_in[15];
    const float* w3_1 = (const float*)d_in[16];
    const float* s3_1 = (const float*)d_in[17];
    const float* o3_1 = (const float*)d_in[18];
    const float* w4   = (const float*)d_in[19];
    const float* b4   = (const float*)d_in[20];
    const float* wf1  = (const float*)d_in[21];
    const float* sf1  = (const float*)d_in[22];
    const float* of1  = (const float*)d_in[23];
    const float* wf2  = (const float*)d_in[24];
    const float* sf2  = (const float*)d_in[25];
    const float* of2  = (const float*)d_in[26];
    const float* wf3  = (const float*)d_in[27];
    // d_in[28] = k (int, always 20)

    // workspace layout (floats) — total ~23 MB
    float* xcpm = (float*)d_ws;                             // B*N*192 point-major
    float* xpm8 = xcpm + (size_t)NB * NPTS * 192;           // B*N*8 point-major {x,sq}
    float* g    = xpm8 + (size_t)NB * NPTS * 8;             // B*1024
    float* goff = g + NB * 1024;                            // B*512
    int*   idx  = (int*)(goff + NB * 512);                  // B*N*20
    float* wT4  = (float*)(idx + NB * NPTS * KNN);          // 192*1024
    float* wf1T = wT4 + 192 * 1024;                         // 192*512
    float* wf2T = wf1T + 192 * 512;                         // 512*256
    unsigned short* xsT = (unsigned short*)(wf2T + 512 * 256); // B*256tiles*3072 bf16
    (void)in_sizes; (void)n_in; (void)out_size; (void)ws_size;

    k_transp<<<(1024 * 192 + 255) / 256, 256, 0, stream>>>(w4, wT4, 1024, 192, 192);
    k_transp<<<(512 * 192 + 255) / 256, 256, 0, stream>>>(wf1, wf1T, 512, 1216, 192);
    k_transp<<<(256 * 512 + 255) / 256, 256, 0, stream>>>(wf2, wf2T, 256, 512, 512);
    k_prep<<<NB * NPTS / 256, 256, 0, stream>>>(x, xpm8);
    k_knn_euclid<<<NB * NPTS / 4, 256, 0, stream>>>(xpm8, idx);
    k_edge1<<<NB * NPTS / 4, 256, 0, stream>>>(x, w1_0, s1_0, o1_0, w1_1, s1_1, o1_1, idx, xcpm);
    k_normalize<<<NB * NPTS / 256, 256, 0, stream>>>(xcpm, 0, xsT);
    k_knn_cos<<<NB * NPTS / 32, 512, 0, stream>>>(xsT, idx);
    k_edge23<<<NB * NPTS / 4, 256, 0, stream>>>(xcpm, w2_0, s2_0, o2_0, w2_1, s2_1, o2_1, idx, 0, 64);
    k_normalize<<<NB * NPTS / 256, 256, 0, stream>>>(xcpm, 64, xsT);
    k_knn_cos<<<NB * NPTS / 32, 512, 0, stream>>>(xsT, idx);
    k_edge23<<<NB * NPTS / 4, 256, 0, stream>>>(xcpm, w3_0, s3_0, o3_0, w3_1, s3_1, o3_1, idx, 64, 128);
    k_init_g<<<NB * 1024 / 256, 256, 0, stream>>>(g);
    k_w4pool<<<dim3(NPTS / 64, NB), 256, 0, stream>>>(xcpm, wT4, b4, g);
    k_goff<<<NB * 512, 256, 0, stream>>>(g, wf1, sf1, of1, goff);
    k_tail<<<dim3(NPTS / 16, NB), 256, 0, stream>>>(xcpm, wf1T, sf1, goff, wf2T, sf2, of2, wf3, (float*)d_out);
}

// Round 20
// 1275.069 us; speedup vs baseline: 1.0391x; 1.0391x over previous
//
#include <hip/hip_runtime.h>
#include <hip/hip_bf16.h>
#include <float.h>

#define NPTS 4096
#define NB 4
#define KNN 20

typedef __attribute__((ext_vector_type(8))) short short8v;   // 8 bf16 in 4 VGPRs
typedef __attribute__((ext_vector_type(4))) float f32x4;
typedef unsigned long long u64;

#define MFMA_B16(acc, a, b) acc = __builtin_amdgcn_mfma_f32_16x16x32_bf16((a), (b), (acc), 0, 0, 0)

// 6-product 3-plane bf16 sim: h·h' + h·m' + m·h' + h·l' + l·h' + m·m'
// A/B arrays: [0]=h0 [1]=h1 [2]=m0 [3]=m1 [4]=l0 [5]=l1 (halves of K=64)
#define SIM6(P, R, A, B) \
    MFMA_B16(P, A[0], B[0]); MFMA_B16(R, A[1], B[1]); \
    MFMA_B16(P, A[0], B[2]); MFMA_B16(R, A[1], B[3]); \
    MFMA_B16(P, A[2], B[0]); MFMA_B16(R, A[3], B[1]); \
    MFMA_B16(P, A[0], B[4]); MFMA_B16(R, A[1], B[5]); \
    MFMA_B16(P, A[4], B[0]); MFMA_B16(R, A[5], B[1]); \
    MFMA_B16(P, A[2], B[2]); MFMA_B16(R, A[3], B[3]);

__device__ __forceinline__ float lrelu(float x) { return x > 0.f ? x : 0.2f * x; }

__device__ __forceinline__ void atomicMaxF(float* addr, float val) {
    int* ia = (int*)addr;
    int old = *ia;
    while (__int_as_float(old) < val) {
        int assumed = old;
        old = atomicCAS(ia, assumed, __float_as_int(val));
        if (old == assumed) break;
    }
}

// round-to-nearest-even fp32 -> bf16 bits
__device__ __forceinline__ unsigned bf16rne(float x) {
    unsigned u = __float_as_uint(x);
    return (u + 0x7fffu + ((u >> 16) & 1u)) >> 16;
}

// fp32 -> uint key where SMALLER key = LARGER float (total order, no NaN inputs).
// key64 = (key32<<32)|idx : ascending sort = (value desc, idx asc) == top_k tie order.
__device__ __forceinline__ unsigned sortkey_desc(float v) {
    unsigned u = __float_as_uint(v);
    unsigned s = (u & 0x80000000u) ? ~u : (u | 0x80000000u);  // ascending int == ascending float
    return ~s;                                                 // invert: ascending key == descending float
}

// 64-lane bitonic sort, ascending by u64 key. Each lane holds one element.
__device__ __forceinline__ u64 bitonic64(u64 e, int ln) {
#pragma unroll
    for (int k = 2; k <= 64; k <<= 1) {
#pragma unroll
        for (int j = k >> 1; j > 0; j >>= 1) {
            u64 o = __shfl_xor(e, j);
            bool keepMin = (((ln & k) == 0) == ((ln & j) == 0));
            u64 mn = e < o ? e : o;
            u64 mx = e < o ? o : e;
            e = keepMin ? mn : mx;
        }
    }
    return e;
}

// Merge current top-20 (lanes 0..19 of 'topk', sorted asc by key) with 'cnt' buffered
// candidates in LDS 'buf'. Updates topk (lanes 0..19), threshold key, resets cnt.
__device__ __forceinline__ void topk_merge(u64& topk, unsigned& thk, int& cnt,
                                           const u64* __restrict__ buf, int ln) {
    u64 e = (ln < 20) ? topk : ((ln - 20) < cnt ? buf[ln - 20] : ~0ull);
    e = bitonic64(e, ln);
    topk = e;
    u64 e19 = __shfl(e, 19);
    thk = (unsigned)(e19 >> 32);
    cnt = 0;
}

// ---------------- generic transpose: dst[c][r] = src[r][c0..] ----------------
__global__ void k_transp(const float* __restrict__ src, float* __restrict__ dst,
                         int rows, int srcld, int cols) {
    int i = blockIdx.x * 256 + threadIdx.x;
    if (i >= rows * cols) return;
    int r = i % rows, c = i / rows;              // writes coalesced
    dst[c * rows + r] = src[(size_t)r * srcld + c];
}

// ---------------- prep for euclid knn: point-major pack {x0..x5, sq, 0} ----------------
__global__ void k_prep(const float* __restrict__ x, float* __restrict__ xpm8) {
    int i = blockIdx.x * 256 + threadIdx.x;   // b*N + n
    int b = i >> 12, n = i & 4095;
    const float* xb = x + b * 6 * NPTS;
    float v[6]; float s = 0.f;
#pragma unroll
    for (int c = 0; c < 6; c++) { v[c] = xb[c * NPTS + n]; s += v[c] * v[c]; }
    float* o = xpm8 + (size_t)i * 8;
    *(float4*)(o)     = make_float4(v[0], v[1], v[2], v[3]);
    *(float4*)(o + 4) = make_float4(v[4], v[5], s, 0.f);
}

// ---------------- euclid knn v6: point-major b128 loads + bootstrap + batched bitonic ----------------
__global__ __launch_bounds__(256) void k_knn_euclid(const float* __restrict__ xpm8,
                                                    int* __restrict__ idx) {
    __shared__ u64 ebuf[4][44];
    int t = threadIdx.x;
    int w = t >> 6, ln = t & 63;
    int qid = blockIdx.x * 4 + w;
    int b = qid >> 12;
    const float* pb = xpm8 + (((size_t)b) << 12) * 8;
    const float* qp = xpm8 + (size_t)qid * 8;
    float4 qlo = *(const float4*)qp;
    float4 qhi = *(const float4*)(qp + 4);
    float sqn = qhi.z;
    u64 topk;
    unsigned thk;
    int cnt = 0;
    u64* bq = ebuf[w];
    // bootstrap: exact top-20 of candidates 0..63 via one full sort
    {
        const float* cp = pb + ln * 8;
        float4 lo = *(const float4*)cp, hi = *(const float4*)(cp + 4);
        float dot = qlo.x * lo.x + qlo.y * lo.y + qlo.z * lo.z + qlo.w * lo.w
                  + qhi.x * hi.x + qhi.y * hi.y;
        float sv = -(sqn - 2.f * dot + hi.z);
        u64 e = ((u64)sortkey_desc(sv) << 32) | (unsigned)ln;
        e = bitonic64(e, ln);
        topk = e;
        thk = (unsigned)(__shfl(e, 19) >> 32);
    }
    for (int t0 = 64; t0 < NPTS; t0 += 64) {
        int m = t0 + ln;
        const float* cp = pb + (size_t)m * 8;
        float4 lo = *(const float4*)cp, hi = *(const float4*)(cp + 4);
        float dot = qlo.x * lo.x + qlo.y * lo.y + qlo.z * lo.z + qlo.w * lo.w
                  + qhi.x * hi.x + qhi.y * hi.y;
        float sv = -(sqn - 2.f * dot + hi.z);        // top-k of -d, exactly as reference
        unsigned key = sortkey_desc(sv);
        bool pass = key < thk;                        // strictly better than current 20th
        u64 mask = __ballot(pass);
        if (!mask) continue;
        u64 key64 = ((u64)key << 32) | (unsigned)m;
        int cA = __popcll(mask & 0xFFFFFFFFull);
        int cB = __popcll(mask >> 32);
        if (cA) {
            if (cnt + cA > 44) topk_merge(topk, thk, cnt, bq, ln);
            if (pass && ln < 32) bq[cnt + __popcll(mask & ((1ull << ln) - 1))] = key64;
            cnt += cA;
        }
        if (cB) {
            if (cnt + cB > 44) topk_merge(topk, thk, cnt, bq, ln);
            if (pass && ln >= 32) bq[cnt + __popcll((mask >> 32) & ((1ull << (ln - 32)) - 1))] = key64;
            cnt += cB;
        }
    }
    if (cnt) topk_merge(topk, thk, cnt, bq, ln);
    if (ln < KNN) idx[qid * KNN + ln] = (int)(topk & 0xFFFFFFFFull);
}

// ---------------- cosine knn v22: v20 base (32q/block, 4 waves) + XCD-aware block swizzle ----------------
// xsT: [b][tile16][plane(3)][half(2)][kg(4)][lp(16)][8ch] bf16. Fragment load = base + ln*8.
// Swizzle: logical bid = (hw_bid & 7)*64 + hw_bid>>3 (bijective, 512 = 8*64). Each XCD's
// round-robin share maps to 64 consecutive logical blocks = half of ONE batch slice
// (1.57 MB < 4 MB per-XCD L2) -> B-fragments become L2-resident (FETCH was 4x input size).
__global__ __launch_bounds__(256) void k_knn_cos(const unsigned short* __restrict__ xsT,
                                                 int* __restrict__ idx) {
    __shared__ float simb[32][260];      // 33.3 KB; rows 0-15 = set0, 16-31 = set1
    __shared__ u64 bufp[32][44];         // 11.3 KB per-query candidate buffers
    int t = threadIdx.x;
    int w = t >> 6, ln = t & 63;
    int bid = (int)(blockIdx.x & 7) * 64 + ((int)blockIdx.x >> 3);   // XCD-contiguous
    int b = bid >> 7;                    // 128 blocks per batch
    int q0blk = (bid & 127) * 32;
    int lp = ln & 15;                    // point-in-tile (A row / B col)
    const unsigned short* xsb = xsT + (size_t)b * 256 * 3072;
    // A fragments: two query tiles x 6 coalesced 1KB loads
    const unsigned short* qt0 = xsb + (size_t)(q0blk >> 4) * 3072 + ln * 8;
    const unsigned short* qt1 = qt0 + 3072;
    short8v A0[6], A1[6];
#pragma unroll
    for (int p = 0; p < 6; p++) {
        A0[p] = *(const short8v*)(qt0 + p * 512);
        A1[p] = *(const short8v*)(qt1 + p * 512);
    }
    u64 topk[8];
    unsigned thk[8];
    int cnt[8] = {0, 0, 0, 0, 0, 0, 0, 0};
    for (int strip = 0; strip < 16; strip++) {
        // ---- compute: 16 cand-tiles; wave w owns 4, processed in pairs ----
#pragma unroll
        for (int tp = 0; tp < 2; tp++) {
            int tt0 = w * 4 + tp * 2;            // strip-local tile index (pair base)
            const unsigned short* tb0 = xsb + (size_t)(strip * 16 + tt0) * 3072 + ln * 8;
            const unsigned short* tb1 = tb0 + 3072;
            short8v Ba[6], Bb[6];
#pragma unroll
            for (int p = 0; p < 6; p++) {
                Ba[p] = *(const short8v*)(tb0 + p * 512);
                Bb[p] = *(const short8v*)(tb1 + p * 512);
            }
            f32x4 p00 = {0.f,0.f,0.f,0.f}, r00 = {0.f,0.f,0.f,0.f};
            f32x4 p01 = {0.f,0.f,0.f,0.f}, r01 = {0.f,0.f,0.f,0.f};
            f32x4 p10 = {0.f,0.f,0.f,0.f}, r10 = {0.f,0.f,0.f,0.f};
            f32x4 p11 = {0.f,0.f,0.f,0.f}, r11 = {0.f,0.f,0.f,0.f};
            SIM6(p00, r00, A0, Ba); SIM6(p01, r01, A0, Bb);
            SIM6(p10, r10, A1, Ba); SIM6(p11, r11, A1, Bb);
            f32x4 s00 = p00 + r00, s01 = p01 + r01;
            f32x4 s10 = p10 + r10, s11 = p11 + r11;
            // D layout: col = lane&15 (candidate), row = (lane>>4)*4 + reg (query)
            int row = (ln >> 4) * 4;
            int colL = tt0 * 16 + lp;            // strip-local column
#pragma unroll
            for (int r = 0; r < 4; r++) {
                simb[row + r][colL]           = s00[r];
                simb[row + r][colL + 16]      = s01[r];
                simb[16 + row + r][colL]      = s10[r];
                simb[16 + row + r][colL + 16] = s11[r];
            }
        }
        __syncthreads();
        // ---- select: wave w scans queries w*8..w*8+7 over the 256-cand strip ----
#pragma unroll
        for (int q = 0; q < 8; q++) {
            int lq = w * 8 + q;
            u64* bq = bufp[lq];
            int j0 = 0;
            if (strip == 0) {
                // exact top-20 of candidates 0..63 via one full sort
                float sv = simb[lq][ln];
                u64 e = ((u64)sortkey_desc(sv) << 32) | (unsigned)ln;
                e = bitonic64(e, ln);
                topk[q] = e;
                thk[q] = (unsigned)(__shfl(e, 19) >> 32);
                j0 = 1;
            }
            for (int j = j0; j < 4; j++) {
                float sv = simb[lq][j * 64 + ln];
                unsigned key = sortkey_desc(sv);
                bool pass = key < thk[q];              // strictly better than 20th
                u64 mask = __ballot(pass);
                if (!mask) continue;
                u64 key64 = ((u64)key << 32) | (unsigned)(strip * 256 + j * 64 + ln);
                int cA = __popcll(mask & 0xFFFFFFFFull);
                int cB = __popcll(mask >> 32);
                if (cA) {
                    if (cnt[q] + cA > 44) topk_merge(topk[q], thk[q], cnt[q], bq, ln);
                    if (pass && ln < 32) bq[cnt[q] + __popcll(mask & ((1ull << ln) - 1))] = key64;
                    cnt[q] += cA;
                }
                if (cB) {
                    if (cnt[q] + cB > 44) topk_merge(topk[q], thk[q], cnt[q], bq, ln);
                    if (pass && ln >= 32) bq[cnt[q] + __popcll((mask >> 32) & ((1ull << (ln - 32)) - 1))] = key64;
                    cnt[q] += cB;
                }
            }
        }
        __syncthreads();
    }
#pragma unroll
    for (int q = 0; q < 8; q++) {
        int lq = w * 8 + q;
        if (cnt[q]) topk_merge(topk[q], thk[q], cnt[q], bufp[lq], ln);
        if (ln < KNN) {
            int qid = (b << 12) + q0blk + lq;
            idx[(size_t)qid * KNN + ln] = (int)(topk[q] & 0xFFFFFFFFull);
        }
    }
}

// ---------------- normalize 64 cols of point-major xcpm -> tile-packed 3-plane bf16 xsT ----------------
// xsT[b][tile16][plane][half][kg][lp][8ch]: x_norm = h+m+l (RNE at each stage)
__global__ void k_normalize(const float* __restrict__ xcpm, int coff,
                            unsigned short* __restrict__ xsT) {
    int pid = blockIdx.x * 256 + threadIdx.x;
    int b = pid >> 12, n = pid & 4095;
    const float* p = xcpm + (size_t)pid * 192 + coff;
    float s = 0.f;
#pragma unroll
    for (int c4 = 0; c4 < 16; c4++) {
        float4 v = *(const float4*)(p + c4 * 4);
        s += v.x * v.x + v.y * v.y + v.z * v.z + v.w * v.w;
    }
    float inv = 1.f / (sqrtf(s) + 1e-8f);
    unsigned short* q = xsT + (size_t)(b * 256 + (n >> 4)) * 3072 + (n & 15) * 8;
#pragma unroll
    for (int c4 = 0; c4 < 16; c4++) {
        float4 v = *(const float4*)(p + c4 * 4);
        float f[4] = {v.x * inv, v.y * inv, v.z * inv, v.w * inv};
        unsigned short hh[4], mm[4], ll[4];
#pragma unroll
        for (int j = 0; j < 4; j++) {
            float x = f[j];
            unsigned hb = bf16rne(x);
            float hf = __uint_as_float(hb << 16);
            float r1 = x - hf;                       // exact
            unsigned mb = bf16rne(r1);
            float mf = __uint_as_float(mb << 16);
            float r2 = r1 - mf;                      // exact
            unsigned lb = bf16rne(r2);
            hh[j] = (unsigned short)hb; mm[j] = (unsigned short)mb; ll[j] = (unsigned short)lb;
        }
        int h = c4 >> 3, kg = (c4 >> 1) & 3, off4 = (c4 & 1) * 4;
        int base = h * 512 + kg * 128 + off4;        // plane 0; +1024/short-plane stride
        *(ushort4*)(q + base)        = make_ushort4(hh[0], hh[1], hh[2], hh[3]);
        *(ushort4*)(q + base + 1024) = make_ushort4(mm[0], mm[1], mm[2], mm[3]);
        *(ushort4*)(q + base + 2048) = make_ushort4(ll[0], ll[1], ll[2], ll[3]);
    }
}

// ---------------- EdgeConv 1: 6ch (channel-major x), 12->64->64, wave-per-point ----------------
__global__ __launch_bounds__(256) void k_edge1(const float* __restrict__ x,
    const float* __restrict__ w0, const float* __restrict__ s0, const float* __restrict__ o0,
    const float* __restrict__ w1, const float* __restrict__ s1, const float* __restrict__ o1,
    const int* __restrict__ idx, float* __restrict__ xcpm) {
    __shared__ float es[4][16];
    __shared__ float h0s[4][64];
    int t = threadIdx.x;
    int w = t >> 6, o = t & 63;
    int pid = blockIdx.x * 4 + w;
    int b = pid >> 12, n = pid & 4095;
    const float* xb = x + b * 6 * NPTS;
    float w0r[12];
    const float* w0p = w0 + o * 12;
#pragma unroll
    for (int c4 = 0; c4 < 3; c4++) {
        float4 v = *(const float4*)(w0p + c4 * 4);
        w0r[c4 * 4] = v.x; w0r[c4 * 4 + 1] = v.y; w0r[c4 * 4 + 2] = v.z; w0r[c4 * 4 + 3] = v.w;
    }
    float w1r[64];
    const float* w1p = w1 + o * 64;
#pragma unroll
    for (int c4 = 0; c4 < 16; c4++) {
        float4 v = *(const float4*)(w1p + c4 * 4);
        w1r[c4 * 4] = v.x; w1r[c4 * 4 + 1] = v.y; w1r[c4 * 4 + 2] = v.z; w1r[c4 * 4 + 3] = v.w;
    }
    float sv0 = s0[o], ov0 = o0[o], sv1 = s1[o], ov1 = o1[o];
    float cv = 0.f;
    if (o < 6) { cv = xb[o * NPTS + n]; es[w][6 + o] = cv; }
    if (o >= 12 && o < 16) es[w][o] = 0.f;
    float acc = -FLT_MAX;
    const int* ib = idx + pid * KNN;
    for (int kk = 0; kk < KNN; kk++) {
        int j = ib[kk] & 4095;
        if (o < 6) es[w][o] = xb[o * NPTS + j] - cv;
        float h = 0.f;
#pragma unroll
        for (int c4 = 0; c4 < 3; c4++) {
            float4 e4 = *(const float4*)&es[w][c4 * 4];
            h += w0r[c4 * 4] * e4.x + w0r[c4 * 4 + 1] * e4.y + w0r[c4 * 4 + 2] * e4.z + w0r[c4 * 4 + 3] * e4.w;
        }
        h = lrelu(h * sv0 + ov0);
        h0s[w][o] = h;
        float h2 = 0.f;
#pragma unroll
        for (int c4 = 0; c4 < 16; c4++) {
            float4 h4 = *(const float4*)&h0s[w][c4 * 4];
            h2 += w1r[c4 * 4] * h4.x + w1r[c4 * 4 + 1] * h4.y + w1r[c4 * 4 + 2] * h4.z + w1r[c4 * 4 + 3] * h4.w;
        }
        h2 = lrelu(h2 * sv1 + ov1);
        acc = fmaxf(acc, h2);
    }
    xcpm[(size_t)pid * 192 + o] = acc;
}

// ---------------- EdgeConv 2/3 v3: channel-outer / neighbor-inner, no weight spills ----------------
// Stage 20 neighbor diffs in LDS once; 20 per-neighbor accumulators in VGPRs; the thread's
// weight float4 is re-loaded per channel-tile per point (L1-hot) instead of spilling 128 regs.
__global__ __launch_bounds__(256) void k_edge23(const float* __restrict__ xcpm,
    const float* __restrict__ w0, const float* __restrict__ s0, const float* __restrict__ o0,
    const float* __restrict__ w1, const float* __restrict__ s1, const float* __restrict__ o1,
    const int* __restrict__ idx, int ci, int co) {
    __shared__ float cs[4][64];          // 1 KB
    __shared__ float es[4][KNN][64];     // 20 KB neighbor diffs
    __shared__ float h0s[4][KNN][64];    // 20 KB layer-0 activations
    int t = threadIdx.x;
    int w = t >> 6, o = t & 63;
    int pid = blockIdx.x * 4 + w;
    int b = pid >> 12;
    float sv0 = s0[o], ov0 = o0[o], sv1 = s1[o], ov1 = o1[o];
    float cv = xcpm[(size_t)pid * 192 + ci + o];
    cs[w][o] = cv;
    // stage neighbor diffs: 20 independent coalesced 256B gathers
    const int* ib = idx + pid * KNN;
    const float* xb = xcpm + ((size_t)(b * 4096)) * 192 + ci;
#pragma unroll
    for (int j = 0; j < KNN; j++) {
        int jn = ib[j] & 4095;
        es[w][j][o] = xb[(size_t)jn * 192 + o] - cv;
    }
    // center contribution (second half of w0 row)
    const float* w0p = w0 + o * 128;
    float h0b;
    {
        float hb[4] = {0.f, 0.f, 0.f, 0.f};
#pragma unroll
        for (int c4 = 0; c4 < 16; c4++) {
            float4 wv = *(const float4*)(w0p + 64 + c4 * 4);
            float4 c4v = *(const float4*)&cs[w][c4 * 4];
            hb[c4 & 3] += wv.x * c4v.x + wv.y * c4v.y + wv.z * c4v.z + wv.w * c4v.w;
        }
        h0b = (hb[0] + hb[1]) + (hb[2] + hb[3]);
    }
    // layer 0: 20 parallel accumulator chains, weight float4 reloaded per channel tile
    float h0a[KNN];
#pragma unroll
    for (int j = 0; j < KNN; j++) h0a[j] = h0b;
    for (int c4 = 0; c4 < 16; c4++) {
        float4 wv = *(const float4*)(w0p + c4 * 4);
#pragma unroll
        for (int j = 0; j < KNN; j++) {
            float4 e = *(const float4*)&es[w][j][c4 * 4];
            h0a[j] += wv.x * e.x + wv.y * e.y + wv.z * e.z + wv.w * e.w;
        }
    }
#pragma unroll
    for (int j = 0; j < KNN; j++) h0s[w][j][o] = lrelu(h0a[j] * sv0 + ov0);
    // layer 1 (wave-synchronous LDS reuse)
    const float* w1p = w1 + o * 64;
    float h1a[KNN];
#pragma unroll
    for (int j = 0; j < KNN; j++) h1a[j] = 0.f;
    for (int c4 = 0; c4 < 16; c4++) {
        float4 wv = *(const float4*)(w1p + c4 * 4);
#pragma unroll
        for (int j = 0; j < KNN; j++) {
            float4 e = *(const float4*)&h0s[w][j][c4 * 4];
            h1a[j] += wv.x * e.x + wv.y * e.y + wv.z * e.z + wv.w * e.w;
        }
    }
    float acc = -FLT_MAX;
#pragma unroll
    for (int j = 0; j < KNN; j++) acc = fmaxf(acc, lrelu(h1a[j] * sv1 + ov1));
    float* outp = (float*)xcpm;
    outp[(size_t)pid * 192 + co + o] = acc;
}

// ---------------- init g to -inf ----------------
__global__ void k_init_g(float* __restrict__ g) {
    g[blockIdx.x * 256 + threadIdx.x] = -FLT_MAX;
}

// ---------------- w4+pool v2: outer-product 16o x 4tn, 64-pt staged tile, wT4 ----------------
__global__ __launch_bounds__(256) void k_w4pool(const float* __restrict__ xc,
                                                const float* __restrict__ wT4,
                                                const float* __restrict__ b4,
                                                float* __restrict__ g) {
    __shared__ float xcs[192 * 68];   // 64 points, stride 68 (52.2 KB)
    int t = threadIdx.x;
    int b = blockIdx.y;
    int n0 = blockIdx.x * 64;
    const float* xb = xc + (size_t)(b * 4096 + n0) * 192;
    for (int i = t; i < 3072; i += 256) {
        int pt = i / 48, c4 = i - pt * 48;
        float4 v = *(const float4*)(xb + pt * 192 + c4 * 4);
        xcs[(c4 * 4 + 0) * 68 + pt] = v.x; xcs[(c4 * 4 + 1) * 68 + pt] = v.y;
        xcs[(c4 * 4 + 2) * 68 + pt] = v.z; xcs[(c4 * 4 + 3) * 68 + pt] = v.w;
    }
    __syncthreads();
    int o0 = (t >> 2) * 16, qd = t & 3;
    float4 bb[4];
#pragma unroll
    for (int k = 0; k < 4; k++) bb[k] = *(const float4*)(b4 + o0 + k * 4);
    float mx[16];
#pragma unroll
    for (int oo = 0; oo < 16; oo++) mx[oo] = -FLT_MAX;
    for (int sub = 0; sub < 4; sub++) {
        int tn0 = sub * 16 + qd * 4;
        float4 acc[16];
#pragma unroll
        for (int oo = 0; oo < 16; oo++) acc[oo] = (float4){0, 0, 0, 0};
        for (int c = 0; c < 192; c++) {
            float4 x4 = *(const float4*)&xcs[c * 68 + tn0];
            const float* wr = wT4 + c * 1024 + o0;
            float4 wq[4];
#pragma unroll
            for (int k = 0; k < 4; k++) wq[k] = *(const float4*)(wr + k * 4);
#pragma unroll
            for (int oo = 0; oo < 16; oo++) {
                float wv = ((const float*)wq)[oo];
                acc[oo].x += wv * x4.x; acc[oo].y += wv * x4.y;
                acc[oo].z += wv * x4.z; acc[oo].w += wv * x4.w;
            }
        }
#pragma unroll
        for (int oo = 0; oo < 16; oo++) {
            float bias = ((const float*)bb)[oo];
            float4 a = acc[oo];
            float h = fmaxf(fmaxf(lrelu(a.x + bias), lrelu(a.y + bias)),
                            fmaxf(lrelu(a.z + bias), lrelu(a.w + bias)));
            mx[oo] = fmaxf(mx[oo], h);
        }
    }
#pragma unroll
    for (int oo = 0; oo < 16; oo++) {
        float v = mx[oo];
        v = fmaxf(v, __shfl_xor(v, 1));
        v = fmaxf(v, __shfl_xor(v, 2));
        if (qd == 0) atomicMaxF(&g[b * 1024 + o0 + oo], v);
    }
}

// ---------------- goff[b][o] = (wf1[o,192:1216] . g[b]) * sf1[o] + of1[o] ----------------
__global__ __launch_bounds__(256) void k_goff(const float* __restrict__ g,
                                              const float* __restrict__ wf1,
                                              const float* __restrict__ sf1,
                                              const float* __restrict__ of1,
                                              float* __restrict__ goff) {
    int bo = blockIdx.x;
    int b = bo >> 9, o = bo & 511;
    int t = threadIdx.x;
    const float* wr = wf1 + (size_t)o * 1216 + 192;
    const float* gb = g + b * 1024;
    float s = 0.f;
    for (int c = t; c < 1024; c += 256) s += wr[c] * gb[c];
    __shared__ float red[4];
    for (int off = 32; off > 0; off >>= 1) s += __shfl_down(s, off);
    if ((t & 63) == 0) red[t >> 6] = s;
    __syncthreads();
    if (t == 0) {
        float tot = red[0] + red[1] + red[2] + red[3];
        goff[bo] = tot * sf1[o] + of1[o];
    }
}

// ---------------- fused tail v2: outer-product register blocking, transposed weights ----------------
#define TP 20
__global__ __launch_bounds__(256) void k_tail(const float* __restrict__ xc,
                                              const float* __restrict__ wf1T,
                                              const float* __restrict__ sf1,
                                              const float* __restrict__ goff,
                                              const float* __restrict__ wf2T,
                                              const float* __restrict__ sf2,
                                              const float* __restrict__ of2,
                                              const float* __restrict__ wf3,
                                              float* __restrict__ out) {
    __shared__ float xcs[192 * TP];      // 15.4 KB
    __shared__ float h1s[512 * TP];      // 40 KB
    __shared__ float h2s[256 * TP];      // 20 KB
    int t = threadIdx.x;
    int b = blockIdx.y;
    int n0 = blockIdx.x * 16;
    const float* xb = xc + (size_t)(b * 4096 + n0) * 192;
    for (int i = t; i < 768; i += 256) {
        int pt = i / 48, c4 = i - pt * 48;
        float4 v = *(const float4*)(xb + pt * 192 + c4 * 4);
        xcs[(c4 * 4 + 0) * TP + pt] = v.x; xcs[(c4 * 4 + 1) * TP + pt] = v.y;
        xcs[(c4 * 4 + 2) * TP + pt] = v.z; xcs[(c4 * 4 + 3) * TP + pt] = v.w;
    }
    __syncthreads();
    // h1: thread = 8 outputs x 4 points
    {
        int o8 = (t >> 2) * 8, tn0 = (t & 3) * 4;
        float4 acc[8];
#pragma unroll
        for (int oo = 0; oo < 8; oo++) acc[oo] = (float4){0, 0, 0, 0};
        for (int c = 0; c < 192; c++) {
            float4 x4 = *(const float4*)&xcs[c * TP + tn0];
            const float* wr = wf1T + c * 512 + o8;
            float4 w0 = *(const float4*)(wr);
            float4 w1 = *(const float4*)(wr + 4);
            float wq[8] = {w0.x, w0.y, w0.z, w0.w, w1.x, w1.y, w1.z, w1.w};
#pragma unroll
            for (int oo = 0; oo < 8; oo++) {
                acc[oo].x += wq[oo] * x4.x; acc[oo].y += wq[oo] * x4.y;
                acc[oo].z += wq[oo] * x4.z; acc[oo].w += wq[oo] * x4.w;
            }
        }
#pragma unroll
        for (int oo = 0; oo < 8; oo++) {
            int o = o8 + oo;
            float s = sf1[o];
            float gv = goff[b * 512 + o];
            float4 r;
            r.x = lrelu(acc[oo].x * s + gv); r.y = lrelu(acc[oo].y * s + gv);
            r.z = lrelu(acc[oo].z * s + gv); r.w = lrelu(acc[oo].w * s + gv);
            *(float4*)&h1s[o * TP + tn0] = r;
        }
    }
    __syncthreads();
    // h2: thread = 4 outputs x 4 points
    {
        int o4 = (t >> 2) * 4, tn0 = (t & 3) * 4;
        float4 acc[4];
#pragma unroll
        for (int oo = 0; oo < 4; oo++) acc[oo] = (float4){0, 0, 0, 0};
        for (int c = 0; c < 512; c++) {
            float4 x4 = *(const float4*)&h1s[c * TP + tn0];
            float4 w = *(const float4*)(wf2T + c * 256 + o4);
            float wq[4] = {w.x, w.y, w.z, w.w};
#pragma unroll
            for (int oo = 0; oo < 4; oo++) {
                acc[oo].x += wq[oo] * x4.x; acc[oo].y += wq[oo] * x4.y;
                acc[oo].z += wq[oo] * x4.z; acc[oo].w += wq[oo] * x4.w;
            }
        }
#pragma unroll
        for (int oo = 0; oo < 4; oo++) {
            int o = o4 + oo;
            float s = sf2[o], of = of2[o];
            float4 r;
            r.x = lrelu(acc[oo].x * s + of); r.y = lrelu(acc[oo].y * s + of);
            r.z = lrelu(acc[oo].z * s + of); r.w = lrelu(acc[oo].w * s + of);
            *(float4*)&h2s[o * TP + tn0] = r;
        }
    }
    __syncthreads();
    // out: 13 x 16
    if (t < 13 * 16) {
        int o = t >> 4, tn = t & 15;
        const float* wr = wf3 + o * 256;
        float acc = 0.f;
        for (int c4 = 0; c4 < 64; c4++) {
            float4 wv = *(const float4*)(wr + c4 * 4);
            acc += wv.x * h2s[(c4 * 4 + 0) * TP + tn] + wv.y * h2s[(c4 * 4 + 1) * TP + tn]
                 + wv.z * h2s[(c4 * 4 + 2) * TP + tn] + wv.w * h2s[(c4 * 4 + 3) * TP + tn];
        }
        out[((size_t)b * 13 + o) * NPTS + n0 + tn] = acc;
    }
}

extern "C" void kernel_launch(void* const* d_in, const int* in_sizes, int n_in,
                              void* d_out, int out_size, void* d_ws, size_t ws_size,
                              hipStream_t stream) {
    const float* x    = (const float*)d_in[0];
    const float* w1_0 = (const float*)d_in[1];
    const float* s1_0 = (const float*)d_in[2];
    const float* o1_0 = (const float*)d_in[3];
    const float* w1_1 = (const float*)d_in[4];
    const float* s1_1 = (const float*)d_in[5];
    const float* o1_1 = (const float*)d_in[6];
    const float* w2_0 = (const float*)d_in[7];
    const float* s2_0 = (const float*)d_in[8];
    const float* o2_0 = (const float*)d_in[9];
    const float* w2_1 = (const float*)d_in[10];
    const float* s2_1 = (const float*)d_in[11];
    const float* o2_1 = (const float*)d_in[12];
    const float* w3_0 = (const float*)d_in[13];
    const float* s3_0 = (const float*)d_in[14];
    const float* o3_0 = (const float*)d_in[15];
    const float* w3_1 = (const float*)d_in[16];
    const float* s3_1 = (const float*)d_in[17];
    const float* o3_1 = (const float*)d_in[18];
    const float* w4   = (const float*)d_in[19];
    const float* b4   = (const float*)d_in[20];
    const float* wf1  = (const float*)d_in[21];
    const float* sf1  = (const float*)d_in[22];
    const float* of1  = (const float*)d_in[23];
    const float* wf2  = (const float*)d_in[24];
    const float* sf2  = (const float*)d_in[25];
    const float* of2  = (const float*)d_in[26];
    const float* wf3  = (const float*)d_in[27];
    // d_in[28] = k (int, always 20)

    // workspace layout (floats) — total ~23 MB
    float* xcpm = (float*)d_ws;                             // B*N*192 point-major
    float* xpm8 = xcpm + (size_t)NB * NPTS * 192;           // B*N*8 point-major {x,sq}
    float* g    = xpm8 + (size_t)NB * NPTS * 8;             // B*1024
    float* goff = g + NB * 1024;                            // B*512
    int*   idx  = (int*)(goff + NB * 512);                  // B*N*20
    float* wT4  = (float*)(idx + NB * NPTS * KNN);          // 192*1024
    float* wf1T = wT4 + 192 * 1024;                         // 192*512
    float* wf2T = wf1T + 192 * 512;                         // 512*256
    unsigned short* xsT = (unsigned short*)(wf2T + 512 * 256); // B*256tiles*3072 bf16
    (void)in_sizes; (void)n_in; (void)out_size; (void)ws_size;

    k_transp<<<(1024 * 192 + 255) / 256, 256, 0, stream>>>(w4, wT4, 1024, 192, 192);
    k_transp<<<(512 * 192 + 255) / 256, 256, 0, stream>>>(wf1, wf1T, 512, 1216, 192);
    k_transp<<<(256 * 512 + 255) / 256, 256, 0, stream>>>(wf2, wf2T, 256, 512, 512);
    k_prep<<<NB * NPTS / 256, 256, 0, stream>>>(x, xpm8);
    k_knn_euclid<<<NB * NPTS / 4, 256, 0, stream>>>(xpm8, idx);
    k_edge1<<<NB * NPTS / 4, 256, 0, stream>>>(x, w1_0, s1_0, o1_0, w1_1, s1_1, o1_1, idx, xcpm);
    k_normalize<<<NB * NPTS / 256, 256, 0, stream>>>(xcpm, 0, xsT);
    k_knn_cos<<<NB * NPTS / 32, 256, 0, stream>>>(xsT, idx);
    k_edge23<<<NB * NPTS / 4, 256, 0, stream>>>(xcpm, w2_0, s2_0, o2_0, w2_1, s2_1, o2_1, idx, 0, 64);
    k_normalize<<<NB * NPTS / 256, 256, 0, stream>>>(xcpm, 64, xsT);
    k_knn_cos<<<NB * NPTS / 32, 256, 0, stream>>>(xsT, idx);
    k_edge23<<<NB * NPTS / 4, 256, 0, stream>>>(xcpm, w3_0, s3_0, o3_0, w3_1, s3_1, o3_1, idx, 64, 128);
    k_init_g<<<NB * 1024 / 256, 256, 0, stream>>>(g);
    k_w4pool<<<dim3(NPTS / 64, NB), 256, 0, stream>>>(xcpm, wT4, b4, g);
    k_goff<<<NB * 512, 256, 0, stream>>>(g, wf1, sf1, of1, goff);
    k_tail<<<dim3(NPTS / 16, NB), 256, 0, stream>>>(xcpm, wf1T, sf1, goff, wf2T, sf2, of2, wf3, (float*)d_out);
}